// Round 1
// baseline (132.392 us; speedup 1.0000x reference)
//
#include <hip/hip_runtime.h>
#include <hip/hip_bf16.h>
#include <stdint.h>

// TripletLoss (batch-hard-ish semi mining) for n=4096, d=2048, K=4.
// Pipeline:
//   1. prep: fp32 -> bf16 matrix (ws) + row sum-of-squares sq[] (fp32)
//   2. init: neg_min bits = +inf
//   3. gemm: upper-tri 128x128 tiles of A@A^T via bf16 MFMA, fused epilogue:
//        dist = sqrt(max(sq_i+sq_j-2*dot, 1e-12))
//        row-min + col-min (symmetry) -> atomicMin(neg_min)
//        diagonal tiles: write within-identity pairs dist_ap[p*6+idx]
//   4. finalize: loss = mean(relu(ap - an + margin)), prec = mean(an > ap)

#define N_ROWS 4096
#define DIM    2048
#define P_IDS  1024
#define NPAIR  (P_IDS * 6)
#define MARGIN 0.3f
#define BK     64

typedef unsigned short u16;
typedef __attribute__((ext_vector_type(8))) short bf16x8;
typedef __attribute__((ext_vector_type(4))) float f32x4;

__device__ __forceinline__ u16 f2bf(float f) {
    unsigned u = __float_as_uint(f);
    unsigned r = (u + 0x7fffu + ((u >> 16) & 1u)) >> 16;  // RTNE
    return (u16)r;
}

__global__ __launch_bounds__(256) void prep_kernel(const float* __restrict__ in,
                                                   u16* __restrict__ bfm,
                                                   float* __restrict__ sq) {
    const int row = blockIdx.x;
    const int t = threadIdx.x;
    const float4* rp = (const float4*)(in + (size_t)row * DIM);
    float4 v0 = rp[t * 2 + 0];
    float4 v1 = rp[t * 2 + 1];
    float s = v0.x * v0.x + v0.y * v0.y + v0.z * v0.z + v0.w * v0.w
            + v1.x * v1.x + v1.y * v1.y + v1.z * v1.z + v1.w * v1.w;
    uint4 o;
    o.x = (unsigned)f2bf(v0.x) | ((unsigned)f2bf(v0.y) << 16);
    o.y = (unsigned)f2bf(v0.z) | ((unsigned)f2bf(v0.w) << 16);
    o.z = (unsigned)f2bf(v1.x) | ((unsigned)f2bf(v1.y) << 16);
    o.w = (unsigned)f2bf(v1.z) | ((unsigned)f2bf(v1.w) << 16);
    ((uint4*)(bfm + (size_t)row * DIM))[t] = o;
    #pragma unroll
    for (int m = 32; m; m >>= 1) s += __shfl_down(s, m, 64);
    __shared__ float red[4];
    if ((t & 63) == 0) red[t >> 6] = s;
    __syncthreads();
    if (t == 0) sq[row] = red[0] + red[1] + red[2] + red[3];
}

__global__ __launch_bounds__(256) void init_kernel(unsigned* __restrict__ neg_bits) {
    int i = blockIdx.x * 256 + threadIdx.x;
    if (i < N_ROWS) neg_bits[i] = 0x7F800000u;  // +inf
}

__global__ __launch_bounds__(256) void gemm_kernel(const u16* __restrict__ bfm,
                                                   const float* __restrict__ sq,
                                                   unsigned* __restrict__ neg_bits,
                                                   float* __restrict__ dist_ap) {
    const int bj = blockIdx.x;
    const int bi = blockIdx.y;
    if (bj < bi) return;  // upper triangle only (symmetry)
    __shared__ u16 As[128][BK];
    __shared__ u16 Bs[128][BK];
    const int t = threadIdx.x;
    const int lane = t & 63;
    const int wave = t >> 6;
    const int wr = (wave >> 1) * 64;   // wave row offset in tile
    const int wc = (wave & 1) * 64;    // wave col offset in tile
    const int lr = lane & 15;          // fragment row/col selector
    const int lk = (lane >> 4) * 8;    // k-offset within 32
    f32x4 acc[4][4] = {};

    const int rowA0 = bi * 128;
    const int rowB0 = bj * 128;
    const int srcRow = lane >> 3;        // 0..7 within 8-row chunk
    const int srcCol = (lane & 7) * 8;   // bf16 col offset (16B granules)

    for (int kk = 0; kk < DIM; kk += BK) {
        __syncthreads();
        #pragma unroll
        for (int is = 0; is < 4; ++is) {
            const int chunk = is * 4 + wave;  // wave-uniform, 0..15
            const int r = chunk * 8 + srcRow;
            const u16* gA = bfm + (size_t)(rowA0 + r) * DIM + kk + srcCol;
            const u16* gB = bfm + (size_t)(rowB0 + r) * DIM + kk + srcCol;
            __builtin_amdgcn_global_load_lds(
                (const __attribute__((address_space(1))) void*)gA,
                (__attribute__((address_space(3))) void*)((char*)&As[0][0] + chunk * 1024),
                16, 0, 0);
            __builtin_amdgcn_global_load_lds(
                (const __attribute__((address_space(1))) void*)gB,
                (__attribute__((address_space(3))) void*)((char*)&Bs[0][0] + chunk * 1024),
                16, 0, 0);
        }
        __syncthreads();
        #pragma unroll
        for (int ks = 0; ks < BK / 32; ++ks) {
            bf16x8 af[4], bfr[4];
            #pragma unroll
            for (int m = 0; m < 4; ++m)
                af[m] = *(const bf16x8*)&As[wr + m * 16 + lr][ks * 32 + lk];
            #pragma unroll
            for (int n = 0; n < 4; ++n)
                bfr[n] = *(const bf16x8*)&Bs[wc + n * 16 + lr][ks * 32 + lk];
            #pragma unroll
            for (int m = 0; m < 4; ++m)
                #pragma unroll
                for (int n = 0; n < 4; ++n)
                    acc[m][n] = __builtin_amdgcn_mfma_f32_16x16x32_bf16(
                        af[m], bfr[n], acc[m][n], 0, 0, 0);
        }
    }

    // ---- fused epilogue ----
    const bool diag = (bi == bj);
    const int crow_base = rowA0 + wr + (lane >> 4) * 4;  // + m*16 + r
    const int ccol_base = rowB0 + wc + (lane & 15);      // + n*16
    float rowmin[4][4];
    float colmin[4];
    #pragma unroll
    for (int m = 0; m < 4; ++m)
        #pragma unroll
        for (int r = 0; r < 4; ++r) rowmin[m][r] = INFINITY;
    #pragma unroll
    for (int n = 0; n < 4; ++n) colmin[n] = INFINITY;

    #pragma unroll
    for (int m = 0; m < 4; ++m) {
        #pragma unroll
        for (int n = 0; n < 4; ++n) {
            const int gcol = ccol_base + n * 16;
            const float sqc = sq[gcol];
            #pragma unroll
            for (int r = 0; r < 4; ++r) {
                const int grow = crow_base + m * 16 + r;
                const float d2 = sq[grow] + sqc - 2.0f * acc[m][n][r];
                const float d = sqrtf(fmaxf(d2, 1e-12f));
                float cand = d;
                if (diag && ((grow >> 2) == (gcol >> 2))) {
                    if (grow < gcol) {  // within-identity pair (a<b)
                        const int p = grow >> 2;
                        const int a = grow & 3, b = gcol & 3;
                        const int idx = (a * (7 - a)) / 2 + (b - a - 1);
                        dist_ap[p * 6 + idx] = d;
                    }
                    cand = INFINITY;  // mask positives from negative mining
                }
                rowmin[m][r] = fminf(rowmin[m][r], cand);
                colmin[n] = fminf(colmin[n], cand);
            }
        }
    }
    // row-min: reduce across the 16 lanes sharing (lane>>4) (they span cols)
    #pragma unroll
    for (int m = 0; m < 4; ++m)
        #pragma unroll
        for (int r = 0; r < 4; ++r) {
            float v = rowmin[m][r];
            v = fminf(v, __shfl_xor(v, 1, 64));
            v = fminf(v, __shfl_xor(v, 2, 64));
            v = fminf(v, __shfl_xor(v, 4, 64));
            v = fminf(v, __shfl_xor(v, 8, 64));
            if ((lane & 15) == 0) {
                const int grow = crow_base + m * 16 + r;
                atomicMin(&neg_bits[grow], __float_as_uint(v));
            }
        }
    // col-min (transpose contribution): reduce across lane>>4 groups
    if (!diag) {
        #pragma unroll
        for (int n = 0; n < 4; ++n) {
            float v = colmin[n];
            v = fminf(v, __shfl_xor(v, 16, 64));
            v = fminf(v, __shfl_xor(v, 32, 64));
            if ((lane >> 4) == 0) {
                atomicMin(&neg_bits[ccol_base + n * 16], __float_as_uint(v));
            }
        }
    }
}

__global__ __launch_bounds__(256) void finalize_kernel(const unsigned* __restrict__ neg_bits,
                                                       const float* __restrict__ dist_ap,
                                                       float* __restrict__ out) {
    const int t = threadIdx.x;
    float sum = 0.f, cnt = 0.f;
    for (int e = t; e < NPAIR; e += 256) {
        const int p = e / 6;
        const int idx = e - p * 6;
        const int a = (idx < 3) ? 0 : ((idx < 5) ? 1 : 2);  // triu jj for K=4
        const float an = __uint_as_float(neg_bits[p * 4 + a]);
        const float ap = dist_ap[e];
        sum += fmaxf(ap - an + MARGIN, 0.f);
        cnt += (an > ap) ? 1.f : 0.f;
    }
    #pragma unroll
    for (int m = 32; m; m >>= 1) {
        sum += __shfl_down(sum, m, 64);
        cnt += __shfl_down(cnt, m, 64);
    }
    __shared__ float rs[4], rc[4];
    if ((t & 63) == 0) { rs[t >> 6] = sum; rc[t >> 6] = cnt; }
    __syncthreads();
    if (t == 0) {
        out[0] = (rs[0] + rs[1] + rs[2] + rs[3]) / (float)NPAIR;
        out[1] = (rc[0] + rc[1] + rc[2] + rc[3]) / (float)NPAIR;
    }
}

extern "C" void kernel_launch(void* const* d_in, const int* in_sizes, int n_in,
                              void* d_out, int out_size, void* d_ws, size_t ws_size,
                              hipStream_t stream) {
    const float* inputs = (const float*)d_in[0];
    float* out = (float*)d_out;
    char* ws = (char*)d_ws;
    u16* bfm = (u16*)ws;                                       // 16 MiB
    float* sq = (float*)(ws + (size_t)N_ROWS * DIM * 2);       // 16 KiB
    unsigned* neg_bits = (unsigned*)((char*)sq + N_ROWS * 4);  // 16 KiB
    float* dist_ap = (float*)((char*)neg_bits + N_ROWS * 4);   // 24 KiB

    prep_kernel<<<N_ROWS, 256, 0, stream>>>(inputs, bfm, sq);
    init_kernel<<<(N_ROWS + 255) / 256, 256, 0, stream>>>(neg_bits);
    dim3 grid(32, 32);
    gemm_kernel<<<grid, 256, 0, stream>>>(bfm, sq, neg_bits, dist_ap);
    finalize_kernel<<<1, 256, 0, stream>>>(neg_bits, dist_ap, out);
}